// Round 1
// baseline (234.232 us; speedup 1.0000x reference)
//
#include <hip/hip_runtime.h>
#include <math.h>

#define W 512
#define H 512
#define HW (512 * 512)
#define CC 64
#define BB 16

// ---------------------------------------------------------------------------
// Kernel 1: channel-wise max + mean over C=64, vectorized float4 per thread.
// x: [B=16, C=64, H=512, W=512] fp32, planes: [B, 2, H, W] (0=max, 1=mean)
// ---------------------------------------------------------------------------
__global__ __launch_bounds__(256) void reduce_kernel(const float* __restrict__ x,
                                                     float* __restrict__ planes) {
    const int perB = HW / 4;                       // 65536 float4 per image plane
    int t = blockIdx.x * 256 + threadIdx.x;        // global float4 index, exact grid
    int b = t >> 16;                               // t / perB
    int p = t & 65535;                             // t % perB

    const float4* xb = reinterpret_cast<const float4*>(x) + (size_t)b * CC * perB + p;

    float4 v = xb[0];
    float4 mx = v;
    float4 sm = v;
    #pragma unroll 8
    for (int c = 1; c < CC; ++c) {
        float4 u = xb[(size_t)c * perB];
        mx.x = fmaxf(mx.x, u.x);
        mx.y = fmaxf(mx.y, u.y);
        mx.z = fmaxf(mx.z, u.z);
        mx.w = fmaxf(mx.w, u.w);
        sm.x += u.x;
        sm.y += u.y;
        sm.z += u.z;
        sm.w += u.w;
    }
    const float inv = 1.0f / (float)CC;
    float4 av = make_float4(sm.x * inv, sm.y * inv, sm.z * inv, sm.w * inv);

    float4* outb = reinterpret_cast<float4*>(planes) + (size_t)b * 2 * perB;
    outb[p] = mx;
    outb[perB + p] = av;
}

// ---------------------------------------------------------------------------
// Kernel 2: 7x7 conv (pad 3) over the 2 planes + sigmoid.
// Block = (32,8) threads; each block computes a 32x32 output tile for batch b.
// LDS holds the 38x38 halo tile as interleaved float2{max, avg}.
// Each thread computes 4 consecutive rows (register row-blocking) so each
// LDS value is reused across up to 4 (kh,k) pairs.
// ---------------------------------------------------------------------------
__global__ __launch_bounds__(256) void conv_kernel(const float* __restrict__ planes,
                                                   const float* __restrict__ wgt,
                                                   float* __restrict__ out) {
    __shared__ float2 sm[38][40];                  // 38 rows halo, padded stride 40

    const int b   = blockIdx.z;
    const int th0 = blockIdx.y * 32;
    const int tw0 = blockIdx.x * 32;
    const int tid = threadIdx.y * 32 + threadIdx.x;

    const float* pb = planes + (size_t)b * 2 * HW;

    // cooperative halo load (38*38 = 1444 pixels, 2 channels interleaved)
    for (int i = tid; i < 38 * 38; i += 256) {
        int r = i / 38, c = i - r * 38;
        int h = th0 + r - 3;
        int w = tw0 + c - 3;
        float vmax = 0.0f, vavg = 0.0f;
        if (h >= 0 && h < H && w >= 0 && w < W) {
            vmax = pb[h * W + w];
            vavg = pb[HW + h * W + w];
        }
        sm[r][c] = make_float2(vmax, vavg);
    }

    // weights are wave-uniform; compile-time indices -> scalar/register file
    float wm[49], wa[49];
    #pragma unroll
    for (int i = 0; i < 49; ++i) {
        wm[i] = wgt[i];
        wa[i] = wgt[49 + i];
    }

    __syncthreads();

    const int tx = threadIdx.x;                    // output column 0..31
    const int ty = threadIdx.y;                    // row group: rows 4*ty .. 4*ty+3

    float acc0 = 0.f, acc1 = 0.f, acc2 = 0.f, acc3 = 0.f;
    #pragma unroll
    for (int r = 0; r < 10; ++r) {                 // rows 4*ty+r cover kh window of 4 outputs
        #pragma unroll
        for (int kw = 0; kw < 7; ++kw) {
            float2 v = sm[4 * ty + r][tx + kw];
            // output k uses kh = r - k when 0 <= r-k <= 6  (compile-time)
            #pragma unroll
            for (int k = 0; k < 4; ++k) {
                int kh = r - k;
                if (kh >= 0 && kh < 7) {
                    float a = (k == 0) ? acc0 : (k == 1) ? acc1 : (k == 2) ? acc2 : acc3;
                    a = fmaf(v.x, wm[kh * 7 + kw], a);
                    a = fmaf(v.y, wa[kh * 7 + kw], a);
                    if (k == 0) acc0 = a; else if (k == 1) acc1 = a; else if (k == 2) acc2 = a; else acc3 = a;
                }
            }
        }
    }

    float* ob = out + (size_t)b * HW + (size_t)tw0 + tx;
    {
        int h = th0 + 4 * ty;
        ob[(h + 0) * W] = 1.0f / (1.0f + __expf(-acc0));
        ob[(h + 1) * W] = 1.0f / (1.0f + __expf(-acc1));
        ob[(h + 2) * W] = 1.0f / (1.0f + __expf(-acc2));
        ob[(h + 3) * W] = 1.0f / (1.0f + __expf(-acc3));
    }
}

extern "C" void kernel_launch(void* const* d_in, const int* in_sizes, int n_in,
                              void* d_out, int out_size, void* d_ws, size_t ws_size,
                              hipStream_t stream) {
    const float* x   = (const float*)d_in[0];   // [16,64,512,512]
    const float* wgt = (const float*)d_in[1];   // [1,2,7,7]
    float* out = (float*)d_out;                 // [16,1,512,512]
    float* planes = (float*)d_ws;               // [16,2,512,512] scratch (32 MiB)

    // Pass 1: channel reduce. 16*65536 float4 elements / 256 = 4096 blocks.
    reduce_kernel<<<dim3(4096), dim3(256), 0, stream>>>(x, planes);

    // Pass 2: conv + sigmoid. 16x16 tiles x 16 batches.
    conv_kernel<<<dim3(16, 16, 16), dim3(32, 8), 0, stream>>>(planes, wgt, out);
}

// Round 3
// 232.220 us; speedup vs baseline: 1.0087x; 1.0087x over previous
//
#include <hip/hip_runtime.h>
#include <hip/hip_fp16.h>
#include <math.h>

#define W 512
#define H 512
#define HW (512 * 512)
#define CC 64
#define BB 16

typedef float f32x4 __attribute__((ext_vector_type(4)));

// ---------------------------------------------------------------------------
// Kernel 1: channel-wise max + mean over C=64.
// Each thread owns 8 consecutive pixels (2 float4), streams 64 channel planes
// with nontemporal loads, writes interleaved {max, avg} as half2 per pixel.
// x: [16,64,512,512] fp32 -> planes: [16, 512*512] half2 (16 MiB total)
// ---------------------------------------------------------------------------
__global__ __launch_bounds__(256) void reduce_kernel(const float* __restrict__ x,
                                                     __half2* __restrict__ planes) {
    const int perB = HW / 4;                      // 65536 float4 per plane
    int t = blockIdx.x * 256 + threadIdx.x;       // 0 .. 524287
    int b = t >> 15;                              // t / 32768
    int p = (t & 32767) * 2;                      // even float4 index in plane

    const f32x4* xb = reinterpret_cast<const f32x4*>(x) + (size_t)b * CC * perB + p;

    f32x4 mx0 = __builtin_nontemporal_load(xb);
    f32x4 mx1 = __builtin_nontemporal_load(xb + 1);
    f32x4 sm0 = mx0, sm1 = mx1;

    #pragma unroll 8
    for (int c = 1; c < CC; ++c) {
        const f32x4* q = xb + (size_t)c * perB;
        f32x4 a = __builtin_nontemporal_load(q);
        f32x4 bq = __builtin_nontemporal_load(q + 1);
        mx0.x = fmaxf(mx0.x, a.x);  sm0.x += a.x;
        mx0.y = fmaxf(mx0.y, a.y);  sm0.y += a.y;
        mx0.z = fmaxf(mx0.z, a.z);  sm0.z += a.z;
        mx0.w = fmaxf(mx0.w, a.w);  sm0.w += a.w;
        mx1.x = fmaxf(mx1.x, bq.x); sm1.x += bq.x;
        mx1.y = fmaxf(mx1.y, bq.y); sm1.y += bq.y;
        mx1.z = fmaxf(mx1.z, bq.z); sm1.z += bq.z;
        mx1.w = fmaxf(mx1.w, bq.w); sm1.w += bq.w;
    }

    const float inv = 1.0f / (float)CC;
    __half2 h[8];
    h[0] = __floats2half2_rn(mx0.x, sm0.x * inv);
    h[1] = __floats2half2_rn(mx0.y, sm0.y * inv);
    h[2] = __floats2half2_rn(mx0.z, sm0.z * inv);
    h[3] = __floats2half2_rn(mx0.w, sm0.w * inv);
    h[4] = __floats2half2_rn(mx1.x, sm1.x * inv);
    h[5] = __floats2half2_rn(mx1.y, sm1.y * inv);
    h[6] = __floats2half2_rn(mx1.z, sm1.z * inv);
    h[7] = __floats2half2_rn(mx1.w, sm1.w * inv);

    uint4* dst = reinterpret_cast<uint4*>(planes + (size_t)b * HW + p * 4);
    dst[0] = *reinterpret_cast<uint4*>(&h[0]);
    dst[1] = *reinterpret_cast<uint4*>(&h[4]);
}

// ---------------------------------------------------------------------------
// Kernel 2: 7x7 conv (pad 3) over interleaved {max,avg} half2 planes + sigmoid.
// Block = (32,8); 32x32 output tile; 38x38 halo staged in LDS as float2.
// Each thread computes 4 consecutive rows (register row-blocking).
// ---------------------------------------------------------------------------
__global__ __launch_bounds__(256) void conv_kernel(const __half2* __restrict__ planes,
                                                   const float* __restrict__ wgt,
                                                   float* __restrict__ out) {
    __shared__ float2 sm[38][40];

    const int b   = blockIdx.z;
    const int th0 = blockIdx.y * 32;
    const int tw0 = blockIdx.x * 32;
    const int tid = threadIdx.y * 32 + threadIdx.x;

    const __half2* pb = planes + (size_t)b * HW;

    for (int i = tid; i < 38 * 38; i += 256) {
        int r = i / 38, c = i - r * 38;
        int h = th0 + r - 3;
        int w = tw0 + c - 3;
        float2 v = make_float2(0.0f, 0.0f);
        if (h >= 0 && h < H && w >= 0 && w < W) {
            v = __half22float2(pb[h * W + w]);
        }
        sm[r][c] = v;
    }

    float wm[49], wa[49];
    #pragma unroll
    for (int i = 0; i < 49; ++i) {
        wm[i] = wgt[i];
        wa[i] = wgt[49 + i];
    }

    __syncthreads();

    const int tx = threadIdx.x;
    const int ty = threadIdx.y;

    float acc0 = 0.f, acc1 = 0.f, acc2 = 0.f, acc3 = 0.f;
    #pragma unroll
    for (int r = 0; r < 10; ++r) {
        #pragma unroll
        for (int kw = 0; kw < 7; ++kw) {
            float2 v = sm[4 * ty + r][tx + kw];
            #pragma unroll
            for (int k = 0; k < 4; ++k) {
                int kh = r - k;
                if (kh >= 0 && kh < 7) {
                    float a = (k == 0) ? acc0 : (k == 1) ? acc1 : (k == 2) ? acc2 : acc3;
                    a = fmaf(v.x, wm[kh * 7 + kw], a);
                    a = fmaf(v.y, wa[kh * 7 + kw], a);
                    if (k == 0) acc0 = a; else if (k == 1) acc1 = a; else if (k == 2) acc2 = a; else acc3 = a;
                }
            }
        }
    }

    float* ob = out + (size_t)b * HW + (size_t)tw0 + tx;
    {
        int h = th0 + 4 * ty;
        ob[(h + 0) * W] = 1.0f / (1.0f + __expf(-acc0));
        ob[(h + 1) * W] = 1.0f / (1.0f + __expf(-acc1));
        ob[(h + 2) * W] = 1.0f / (1.0f + __expf(-acc2));
        ob[(h + 3) * W] = 1.0f / (1.0f + __expf(-acc3));
    }
}

extern "C" void kernel_launch(void* const* d_in, const int* in_sizes, int n_in,
                              void* d_out, int out_size, void* d_ws, size_t ws_size,
                              hipStream_t stream) {
    const float* x   = (const float*)d_in[0];   // [16,64,512,512]
    const float* wgt = (const float*)d_in[1];   // [1,2,7,7]
    float* out = (float*)d_out;                 // [16,1,512,512]
    __half2* planes = (__half2*)d_ws;           // [16, 512*512] half2 (16 MiB)

    // Pass 1: channel reduce. 524288 threads / 256 = 2048 blocks.
    reduce_kernel<<<dim3(2048), dim3(256), 0, stream>>>(x, planes);

    // Pass 2: conv + sigmoid. 16x16 tiles x 16 batches.
    conv_kernel<<<dim3(16, 16, 16), dim3(32, 8), 0, stream>>>(planes, wgt, out);
}